// Round 1
// baseline (9807.248 us; speedup 1.0000x reference)
//
#include <hip/hip_runtime.h>
#include <math.h>

#define MSZ 1048576ull   // 1024*1024 elements per matrix slot
#define NMAT 33          // matrix 0 = L0, matrices 1..32 = per-batch L

__device__ __forceinline__ float frcp(float x){ return __builtin_amdgcn_rcpf(x); }

// ---------------------------------------------------------------- setup
__global__ void k_init(float* __restrict__ logdet){
  int t = threadIdx.x; if(t < NMAT) logdet[t] = 0.f;
}

__global__ void k_softmax_v(const float* __restrict__ Vc, float* __restrict__ V){
  int i = blockIdx.x*blockDim.x + threadIdx.x;
  if(i >= 1024) return;
  float4 v = ((const float4*)Vc)[i];
  float mx = fmaxf(fmaxf(v.x,v.y), fmaxf(v.z,v.w));
  float e0=__expf(v.x-mx), e1=__expf(v.y-mx), e2=__expf(v.z-mx), e3=__expf(v.w-mx);
  float is = 1.f/(e0+e1+e2+e3);
  ((float4*)V)[i] = make_float4(e0*is, e1*is, e2*is, e3*is);
}

// Pr[b,i] = V[i, x[b,i]];  PrInv = 1/Pr;  y[b] = sum_i log(Pr + 1e-7)
__global__ void k_pr_y(const float* __restrict__ V, const int* __restrict__ x,
                       float* __restrict__ PrInv, float* __restrict__ y){
  int b = blockIdx.x, t = threadIdx.x;
  __shared__ float red[256];
  float acc = 0.f;
  for(int i=t; i<1024; i+=256){
    int xv = x[b*1024+i];
    float pr = V[i*4+xv];
    PrInv[b*1024+i] = 1.f/pr;
    acc += logf(pr + 1e-7f);
  }
  red[t]=acc; __syncthreads();
  for(int s=128;s>0;s>>=1){ if(t<s) red[t]+=red[t+s]; __syncthreads(); }
  if(t==0) y[b]=red[0];
}

// Ws = sigmoid(W) strictly-lower, symmetrized, zero diag
__global__ void k_ws(const float* __restrict__ W, float* __restrict__ Ws){
  int idx = blockIdx.x*256 + threadIdx.x;
  int i = idx>>10, j = idx&1023;
  float v = 0.f;
  if(i != j){
    float w = (i>j) ? W[i*1024+j] : W[j*1024+i];
    v = 1.f/(1.f+__expf(-w));
  }
  Ws[idx]=v;
}

// ---------------------------------------------------------------- sinkhorn + WP
// One thread per (i,j). Writes WP (shifted by -1,-1) into mats[1..32];
// column j==0 values go to col0[b][i] (needed only for the row sums).
__global__ void __launch_bounds__(256) k_sinkhorn(
    const float* __restrict__ Ec, const float* __restrict__ V,
    const float* __restrict__ Ws, const float* __restrict__ PrInv,
    const int* __restrict__ x, float* __restrict__ mats, float* __restrict__ col0){
  int idx = blockIdx.x*256 + threadIdx.x;
  int i = idx>>10, j = idx&1023;
  if(i==0) return;                      // row 0 of WP never needed
  int t = threadIdx.x;
  __shared__ float sE[256][17];
  if(i==j){                             // diagonal blocks are zeroed by (1-eye)
    for(int b=0;b<32;b++)
      mats[(size_t)(1+b)*MSZ + (size_t)(i-1)*1024 + (j-1)] = 0.f;
    return;
  }
  float E[16];
  {
    const float4* p = (const float4*)(Ec + (size_t)idx*16);
    float4 q0=p[0], q1=p[1], q2=p[2], q3=p[3];
    E[0]=__expf(q0.x); E[1]=__expf(q0.y); E[2]=__expf(q0.z); E[3]=__expf(q0.w);
    E[4]=__expf(q1.x); E[5]=__expf(q1.y); E[6]=__expf(q1.z); E[7]=__expf(q1.w);
    E[8]=__expf(q2.x); E[9]=__expf(q2.y); E[10]=__expf(q2.z); E[11]=__expf(q2.w);
    E[12]=__expf(q3.x);E[13]=__expf(q3.y);E[14]=__expf(q3.z); E[15]=__expf(q3.w);
  }
  float s0=0.f;
  #pragma unroll
  for(int q=0;q<16;q++) s0+=E[q];
  float is0 = frcp(s0);
  #pragma unroll
  for(int q=0;q<16;q++) E[q]*=is0;
  float av[4], bv[4];
  {
    float4 va = ((const float4*)V)[i];
    av[0]=va.x; av[1]=va.y; av[2]=va.z; av[3]=va.w;
    float4 vb = ((const float4*)V)[j];
    bv[0]=vb.x; bv[1]=vb.y; bv[2]=vb.z; bv[3]=vb.w;
  }
  for(int it=0; it<40; ++it){
    #pragma unroll
    for(int r=0;r<4;r++){
      float rs = E[4*r]+E[4*r+1]+E[4*r+2]+E[4*r+3];
      float sc = av[r]*frcp(rs+1e-7f);
      E[4*r]*=sc; E[4*r+1]*=sc; E[4*r+2]*=sc; E[4*r+3]*=sc;
    }
    #pragma unroll
    for(int c=0;c<4;c++){
      float cs = E[c]+E[4+c]+E[8+c]+E[12+c];
      float sc = bv[c]*frcp(cs+1e-7f);
      E[c]*=sc; E[4+c]*=sc; E[8+c]*=sc; E[12+c]*=sc;
    }
    float T=0.f;
    #pragma unroll
    for(int q=0;q<16;q++) T+=E[q];
    float u = frcp(T+1e-7f);
    #pragma unroll
    for(int q=0;q<16;q++) E[q]*=u;
  }
  // clip to [0,1]; park in LDS so the x-dependent gather is not a register-array
  // dynamic index (would spill to scratch)
  #pragma unroll
  for(int q=0;q<16;q++) sE[t][q] = fminf(fmaxf(E[q],0.f),1.f);
  float wsij = Ws[idx];
  for(int b=0;b<32;b++){
    int xi = x[b*1024+i];               // uniform per block -> scalar load
    int xj = x[b*1024+j];
    float val = sE[t][(xi<<2)+xj] * wsij * PrInv[b*1024+i] * PrInv[b*1024+j];
    if(j==0) col0[b*1024+i] = val;
    else mats[(size_t)(1+b)*MSZ + (size_t)(i-1)*1024 + (j-1)] = val;
  }
}

// ---------------------------------------------------------------- Laplacian builds
// mats[0] row r (r=0..1022) <- L0[r+1][c+1] = -Ws + 1e-7 (+rowsum on diag)
__global__ void k_l0(const float* __restrict__ Ws, float* __restrict__ mats){
  int r = blockIdx.x, t = threadIdx.x;
  const float* wrow = Ws + (size_t)(r+1)*1024;
  float4 v = ((const float4*)wrow)[t];
  __shared__ float red[256];
  red[t] = v.x+v.y+v.z+v.w;             // full 1024-col row sum
  __syncthreads();
  for(int s=128;s>0;s>>=1){ if(t<s) red[t]+=red[t+s]; __syncthreads(); }
  float rs = red[0];
  float* orow = mats + (size_t)r*1024;
  #pragma unroll
  for(int q=0;q<4;q++){
    int c = 4*t+q;
    if(c<1023){
      float w = wrow[c+1];
      orow[c] = (c==r) ? rs+1e-7f : 1e-7f - w;
    }
  }
}

// in-place: mats[1+b] row r: WP -> L  (diag = full row sum incl col0 stash)
__global__ void k_lb(float* __restrict__ mats, const float* __restrict__ col0){
  int r = blockIdx.x, b = blockIdx.y, t = threadIdx.x;
  float* row = mats + (size_t)(1+b)*MSZ + (size_t)r*1024;
  float4 v = ((const float4*)row)[t];
  bool last = (t==255);                 // col 1023 is padding (poison): exclude
  __shared__ float red[256];
  red[t] = v.x+v.y+v.z + (last?0.f:v.w);
  __syncthreads();
  for(int s=128;s>0;s>>=1){ if(t<s) red[t]+=red[t+s]; __syncthreads(); }
  float rs = red[0] + col0[b*1024 + r + 1];
  int c0 = 4*t;
  float o0 = (c0==r)  ? rs+1e-7f : 1e-7f - v.x;
  float o1 = (c0+1==r)? rs+1e-7f : 1e-7f - v.y;
  float o2 = (c0+2==r)? rs+1e-7f : 1e-7f - v.z;
  float o3 = (c0+3==r)? rs+1e-7f : 1e-7f - v.w;
  if(!last) ((float4*)row)[t] = make_float4(o0,o1,o2,o3);
  else { row[1020]=o0; row[1021]=o1; row[1022]=o2; }
}

// ---------------------------------------------------------------- blocked LU (no pivoting; matrices are strictly diagonally dominant)
// 64x64 diagonal-block LU, one wave per matrix, rows in registers + shuffles.
__global__ void __launch_bounds__(64) k_diag(float* __restrict__ mats,
    float* __restrict__ L11g, float* __restrict__ U11g,
    float* __restrict__ logdet, int k, int nb){
  int m = blockIdx.x;
  const float* A = mats + (size_t)m*MSZ;
  int t = threadIdx.x;
  bool rv = t < nb;
  float row[64];
  #pragma unroll
  for(int q=0;q<64;q++)
    row[q] = (rv && q<nb) ? A[(size_t)(k+t)*1024 + k + q] : ((t==q)?1.f:0.f);
  float slog = 0.f;
  #pragma unroll
  for(int c=0;c<64;c++){
    float piv = __shfl(row[c], c);
    slog += logf(fabsf(piv));           // uniform across lanes; lane0's is kept
    float ip = frcp(piv);
    bool below = t > c;
    float lic = below ? row[c]*ip : 0.f;
    row[c] = below ? lic : row[c];
    if(below) L11g[m*4096 + t*64 + c] = lic;
    #pragma unroll
    for(int q=c+1;q<64;q++){
      float uq = __shfl(row[q], c);
      row[q] = fmaf(-lic, uq, row[q]);  // lic==0 for t<=c -> no-op
    }
  }
  #pragma unroll
  for(int q=0;q<64;q++)
    U11g[m*4096 + t*64 + q] = (q>=t) ? row[q] : 0.f;
  if(t==0) logdet[m] += slog;
}

// L21 = A21 * U11^-1  (thread per trailing row; U11 via uniform scalar loads)
__global__ void __launch_bounds__(256) k_l21(float* __restrict__ mats,
    const float* __restrict__ U11g, int k){
  int m = blockIdx.y;
  float* A = mats + (size_t)m*MSZ;
  const float* __restrict__ U = U11g + m*4096;
  int i = k + 64 + blockIdx.x*256 + threadIdx.x;
  bool act = i < 1023;
  size_t base = (size_t)i*1024 + k;
  float xr[64];
  #pragma unroll
  for(int q=0;q<64;q++) xr[q] = act ? A[base+q] : 0.f;
  #pragma unroll
  for(int p=0;p<64;p++){
    float xp = xr[p]*frcp(U[p*64+p]);
    xr[p] = xp;
    #pragma unroll
    for(int q=p+1;q<64;q++) xr[q] = fmaf(-xp, U[p*64+q], xr[q]);
  }
  if(act){
    #pragma unroll
    for(int q=0;q<64;q++) A[base+q] = xr[q];
  }
}

// U12 = L11^-1 * A12  (thread per trailing column; L11 unit-lower via scalar loads)
__global__ void __launch_bounds__(256) k_trsm(float* __restrict__ mats,
    const float* __restrict__ L11g, int k){
  int m = blockIdx.y;
  float* A = mats + (size_t)m*MSZ;
  const float* __restrict__ L = L11g + m*4096;
  int col = k + 64 + blockIdx.x*256 + threadIdx.x;
  bool act = col < 1023;
  float tv[64];
  #pragma unroll
  for(int r=0;r<64;r++) tv[r] = act ? A[(size_t)(k+r)*1024 + col] : 0.f;
  #pragma unroll
  for(int r=1;r<64;r++){
    float s = tv[r];
    #pragma unroll
    for(int p=0;p<r;p++) s = fmaf(-L[r*64+p], tv[p], s);
    tv[r] = s;
  }
  if(act){
    #pragma unroll
    for(int r=0;r<64;r++) A[(size_t)(k+r)*1024 + col] = tv[r];
  }
}

// A22 -= L21 * U12 : 64x64 tiles, 256 threads, 4x4 micro-tile, fp32
__global__ void __launch_bounds__(256) k_gemm(float* __restrict__ mats, int k){
  int m = blockIdx.z;
  float* A = mats + (size_t)m*MSZ;
  int r0 = k + 64;
  int i0 = r0 + blockIdx.y*64;
  int j0 = r0 + blockIdx.x*64;
  __shared__ float As[64*68];   // transposed: As[kc*68 + ilocal]
  __shared__ float Bs[64*68];   // Bs[kc*68 + jlocal]
  int t = threadIdx.x;
  #pragma unroll
  for(int r4=0;r4<4;r4++){
    int l = t*4 + r4*1024;
    int row = l>>6, c = l&63;
    float4 av = make_float4(0.f,0.f,0.f,0.f);
    if(i0+row < 1023) av = *(const float4*)(A + (size_t)(i0+row)*1024 + k + c);
    As[(c+0)*68+row]=av.x; As[(c+1)*68+row]=av.y; As[(c+2)*68+row]=av.z; As[(c+3)*68+row]=av.w;
    float4 bvv = *(const float4*)(A + (size_t)(k+row)*1024 + j0 + c);
    *(float4*)(Bs + row*68 + c) = bvv;
  }
  __syncthreads();
  int tx = t&15, ty = t>>4;
  float acc[4][4];
  #pragma unroll
  for(int r=0;r<4;r++){
    #pragma unroll
    for(int q=0;q<4;q++) acc[r][q]=0.f;
  }
  #pragma unroll
  for(int c=0;c<64;c++){
    float4 a = *(const float4*)(As + c*68 + ty*4);
    float4 b = *(const float4*)(Bs + c*68 + tx*4);
    acc[0][0]=fmaf(a.x,b.x,acc[0][0]); acc[0][1]=fmaf(a.x,b.y,acc[0][1]);
    acc[0][2]=fmaf(a.x,b.z,acc[0][2]); acc[0][3]=fmaf(a.x,b.w,acc[0][3]);
    acc[1][0]=fmaf(a.y,b.x,acc[1][0]); acc[1][1]=fmaf(a.y,b.y,acc[1][1]);
    acc[1][2]=fmaf(a.y,b.z,acc[1][2]); acc[1][3]=fmaf(a.y,b.w,acc[1][3]);
    acc[2][0]=fmaf(a.z,b.x,acc[2][0]); acc[2][1]=fmaf(a.z,b.y,acc[2][1]);
    acc[2][2]=fmaf(a.z,b.z,acc[2][2]); acc[2][3]=fmaf(a.z,b.w,acc[2][3]);
    acc[3][0]=fmaf(a.w,b.x,acc[3][0]); acc[3][1]=fmaf(a.w,b.y,acc[3][1]);
    acc[3][2]=fmaf(a.w,b.z,acc[3][2]); acc[3][3]=fmaf(a.w,b.w,acc[3][3]);
  }
  #pragma unroll
  for(int r=0;r<4;r++){
    int gi = i0 + ty*4 + r;
    #pragma unroll
    for(int q=0;q<4;q++){
      int gj = j0 + tx*4 + q;
      if(gi<1023 && gj<1023){
        size_t o = (size_t)gi*1024 + gj;
        A[o] -= acc[r][q];
      }
    }
  }
}

__global__ void k_final(const float* __restrict__ y, const float* __restrict__ logdet,
                        float* __restrict__ out){
  int b = threadIdx.x;
  if(b<32) out[b] = y[b] + logdet[1+b] - logdet[0];
}

// ---------------------------------------------------------------- launch
extern "C" void kernel_launch(void* const* d_in, const int* in_sizes, int n_in,
                              void* d_out, int out_size, void* d_ws, size_t ws_size,
                              hipStream_t stream){
  (void)in_sizes; (void)n_in; (void)out_size; (void)ws_size;
  const int*   x  = (const int*)d_in[0];
  const float* W  = (const float*)d_in[1];
  const float* Vc = (const float*)d_in[2];
  const float* Ec = (const float*)d_in[3];
  float* out = (float*)d_out;

  char* p = (char*)d_ws;
  auto alloc = [&](size_t bytes)->char*{ char* r = p; p += (bytes+255)&~(size_t)255; return r; };
  float* mats   = (float*)alloc((size_t)NMAT*MSZ*4);   // 138.4 MB: L0 + 32 batch matrices
  float* Ws     = (float*)alloc(1048576ull*4);
  float* L11g   = (float*)alloc((size_t)NMAT*4096*4);
  float* U11g   = (float*)alloc((size_t)NMAT*4096*4);
  float* V      = (float*)alloc(4096*4);
  float* PrInv  = (float*)alloc(32768*4);
  float* col0   = (float*)alloc(32768*4);
  float* y      = (float*)alloc(256);
  float* logdet = (float*)alloc(256);

  k_init<<<1,64,0,stream>>>(logdet);
  k_softmax_v<<<4,256,0,stream>>>(Vc, V);
  k_pr_y<<<32,256,0,stream>>>(V, x, PrInv, y);
  k_ws<<<4096,256,0,stream>>>(W, Ws);
  k_sinkhorn<<<4096,256,0,stream>>>(Ec, V, Ws, PrInv, x, mats, col0);
  k_l0<<<1023,256,0,stream>>>(Ws, mats);
  k_lb<<<dim3(1023,32),256,0,stream>>>(mats, col0);

  for(int s=0;s<16;s++){
    int k  = 64*s;
    int nb = (1023-k >= 64) ? 64 : (1023-k);
    k_diag<<<NMAT,64,0,stream>>>(mats, L11g, U11g, logdet, k, nb);
    int rem = 1023 - (k+64);
    if(rem > 0){
      int cb = (rem+255)/256;
      k_l21 <<<dim3(cb,NMAT),256,0,stream>>>(mats, U11g, k);
      k_trsm<<<dim3(cb,NMAT),256,0,stream>>>(mats, L11g, k);
      int nt = (rem+63)/64;
      k_gemm<<<dim3(nt,nt,NMAT),256,0,stream>>>(mats, k);
    }
  }
  k_final<<<1,32,0,stream>>>(y, logdet, out);
}

// Round 2
// 1949.997 us; speedup vs baseline: 5.0294x; 5.0294x over previous
//
#include <hip/hip_runtime.h>
#include <math.h>

#define MSZ 1048576ull   // 1024*1024 elements per matrix slot
#define NMAT 33          // matrix 0 = L0, matrices 1..32 = per-batch L

__device__ __forceinline__ float frcp(float x){ return __builtin_amdgcn_rcpf(x); }

// ---------------------------------------------------------------- setup
__global__ void k_init(float* __restrict__ logdet){
  int t = threadIdx.x; if(t < NMAT) logdet[t] = 0.f;
}

__global__ void k_softmax_v(const float* __restrict__ Vc, float* __restrict__ V){
  int i = blockIdx.x*blockDim.x + threadIdx.x;
  if(i >= 1024) return;
  float4 v = ((const float4*)Vc)[i];
  float mx = fmaxf(fmaxf(v.x,v.y), fmaxf(v.z,v.w));
  float e0=__expf(v.x-mx), e1=__expf(v.y-mx), e2=__expf(v.z-mx), e3=__expf(v.w-mx);
  float is = 1.f/(e0+e1+e2+e3);
  ((float4*)V)[i] = make_float4(e0*is, e1*is, e2*is, e3*is);
}

// Pr[b,i] = V[i, x[b,i]];  PrInv = 1/Pr;  y[b] = sum_i log(Pr + 1e-7)
__global__ void k_pr_y(const float* __restrict__ V, const int* __restrict__ x,
                       float* __restrict__ PrInv, float* __restrict__ y){
  int b = blockIdx.x, t = threadIdx.x;
  __shared__ float red[256];
  float acc = 0.f;
  for(int i=t; i<1024; i+=256){
    int xv = x[b*1024+i];
    float pr = V[i*4+xv];
    PrInv[b*1024+i] = 1.f/pr;
    acc += logf(pr + 1e-7f);
  }
  red[t]=acc; __syncthreads();
  for(int s=128;s>0;s>>=1){ if(t<s) red[t]+=red[t+s]; __syncthreads(); }
  if(t==0) y[b]=red[0];
}

// Ws = sigmoid(W) strictly-lower, symmetrized, zero diag
__global__ void k_ws(const float* __restrict__ W, float* __restrict__ Ws){
  int idx = blockIdx.x*256 + threadIdx.x;
  int i = idx>>10, j = idx&1023;
  float v = 0.f;
  if(i != j){
    float w = (i>j) ? W[i*1024+j] : W[j*1024+i];
    v = 1.f/(1.f+__expf(-w));
  }
  Ws[idx]=v;
}

// ---------------------------------------------------------------- sinkhorn + WP
// One thread per (i,j). Writes WP (shifted by -1,-1) into mats[1..32];
// column j==0 values go to col0[b][i] (needed only for the row sums).
__global__ void __launch_bounds__(256) k_sinkhorn(
    const float* __restrict__ Ec, const float* __restrict__ V,
    const float* __restrict__ Ws, const float* __restrict__ PrInv,
    const int* __restrict__ x, float* __restrict__ mats, float* __restrict__ col0){
  int idx = blockIdx.x*256 + threadIdx.x;
  int i = idx>>10, j = idx&1023;
  if(i==0) return;                      // row 0 of WP never needed
  int t = threadIdx.x;
  __shared__ float sE[256][17];
  if(i==j){                             // diagonal blocks are zeroed by (1-eye)
    for(int b=0;b<32;b++)
      mats[(size_t)(1+b)*MSZ + (size_t)(i-1)*1024 + (j-1)] = 0.f;
    return;
  }
  float E[16];
  {
    const float4* p = (const float4*)(Ec + (size_t)idx*16);
    float4 q0=p[0], q1=p[1], q2=p[2], q3=p[3];
    E[0]=__expf(q0.x); E[1]=__expf(q0.y); E[2]=__expf(q0.z); E[3]=__expf(q0.w);
    E[4]=__expf(q1.x); E[5]=__expf(q1.y); E[6]=__expf(q1.z); E[7]=__expf(q1.w);
    E[8]=__expf(q2.x); E[9]=__expf(q2.y); E[10]=__expf(q2.z); E[11]=__expf(q2.w);
    E[12]=__expf(q3.x);E[13]=__expf(q3.y);E[14]=__expf(q3.z); E[15]=__expf(q3.w);
  }
  float s0=0.f;
  #pragma unroll
  for(int q=0;q<16;q++) s0+=E[q];
  float is0 = frcp(s0);
  #pragma unroll
  for(int q=0;q<16;q++) E[q]*=is0;
  float av[4], bv[4];
  {
    float4 va = ((const float4*)V)[i];
    av[0]=va.x; av[1]=va.y; av[2]=va.z; av[3]=va.w;
    float4 vb = ((const float4*)V)[j];
    bv[0]=vb.x; bv[1]=vb.y; bv[2]=vb.z; bv[3]=vb.w;
  }
  for(int it=0; it<40; ++it){
    #pragma unroll
    for(int r=0;r<4;r++){
      float rs = E[4*r]+E[4*r+1]+E[4*r+2]+E[4*r+3];
      float sc = av[r]*frcp(rs+1e-7f);
      E[4*r]*=sc; E[4*r+1]*=sc; E[4*r+2]*=sc; E[4*r+3]*=sc;
    }
    #pragma unroll
    for(int c=0;c<4;c++){
      float cs = E[c]+E[4+c]+E[8+c]+E[12+c];
      float sc = bv[c]*frcp(cs+1e-7f);
      E[c]*=sc; E[4+c]*=sc; E[8+c]*=sc; E[12+c]*=sc;
    }
    float T=0.f;
    #pragma unroll
    for(int q=0;q<16;q++) T+=E[q];
    float u = frcp(T+1e-7f);
    #pragma unroll
    for(int q=0;q<16;q++) E[q]*=u;
  }
  // clip to [0,1]; park in LDS so the x-dependent gather is not a register-array
  // dynamic index (would spill to scratch)
  #pragma unroll
  for(int q=0;q<16;q++) sE[t][q] = fminf(fmaxf(E[q],0.f),1.f);
  float wsij = Ws[idx];
  for(int b=0;b<32;b++){
    int xi = x[b*1024+i];               // uniform per block -> scalar load
    int xj = x[b*1024+j];
    float val = sE[t][(xi<<2)+xj] * wsij * PrInv[b*1024+i] * PrInv[b*1024+j];
    if(j==0) col0[b*1024+i] = val;
    else mats[(size_t)(1+b)*MSZ + (size_t)(i-1)*1024 + (j-1)] = val;
  }
}

// ---------------------------------------------------------------- Laplacian builds
// Matrices padded to 1024x1024: row/col 1023 zero, A[1023][1023]=1 (log 1 = 0).
// All LU tiles are then full 64-aligned blocks with no bounds checks.

// mats[0] row r <- L0[r+1][c+1] = -Ws + 1e-7 (+rowsum on diag), r,c in 0..1022
__global__ void k_l0(const float* __restrict__ Ws, float* __restrict__ mats){
  int r = blockIdx.x, t = threadIdx.x;
  float* orow = mats + (size_t)r*1024;
  if(r == 1023){
    float4 o = make_float4(0.f,0.f,0.f,0.f);
    if(t==255) o.w = 1.f;
    ((float4*)orow)[t] = o;
    return;
  }
  const float* wrow = Ws + (size_t)(r+1)*1024;
  float4 v = ((const float4*)wrow)[t];
  __shared__ float red[256];
  red[t] = v.x+v.y+v.z+v.w;             // full 1024-col row sum (Ws diag = 0)
  __syncthreads();
  for(int s=128;s>0;s>>=1){ if(t<s) red[t]+=red[t+s]; __syncthreads(); }
  float rs = red[0];
  float o[4];
  #pragma unroll
  for(int q=0;q<4;q++){
    int c = 4*t+q;
    if(c==r)          o[q] = rs + 1e-7f;
    else if(c < 1023) o[q] = 1e-7f - wrow[c+1];
    else              o[q] = 0.f;
  }
  ((float4*)orow)[t] = make_float4(o[0],o[1],o[2],o[3]);
}

// in-place: mats[1+b] row r: WP -> L  (diag = full row sum incl col0 stash)
__global__ void k_lb(float* __restrict__ mats, const float* __restrict__ col0){
  int r = blockIdx.x, b = blockIdx.y, t = threadIdx.x;
  float* row = mats + (size_t)(1+b)*MSZ + (size_t)r*1024;
  if(r == 1023){
    float4 o = make_float4(0.f,0.f,0.f,0.f);
    if(t==255) o.w = 1.f;
    ((float4*)row)[t] = o;
    return;
  }
  float4 v = ((const float4*)row)[t];
  bool last = (t==255);                 // col 1023 is padding (poison): exclude
  __shared__ float red[256];
  red[t] = v.x+v.y+v.z + (last?0.f:v.w);
  __syncthreads();
  for(int s=128;s>0;s>>=1){ if(t<s) red[t]+=red[t+s]; __syncthreads(); }
  float rs = red[0] + col0[b*1024 + r + 1];
  int c0 = 4*t;
  float o0 = (c0==r)  ? rs+1e-7f : 1e-7f - v.x;
  float o1 = (c0+1==r)? rs+1e-7f : 1e-7f - v.y;
  float o2 = (c0+2==r)? rs+1e-7f : 1e-7f - v.z;
  float o3 = last ? 0.f : ((c0+3==r)? rs+1e-7f : 1e-7f - v.w);
  ((float4*)row)[t] = make_float4(o0,o1,o2,o3);
}

// ---------------------------------------------------------------- blocked LU (no pivoting; matrices are strictly diagonally dominant)
// 64x64 diagonal-block LU, one wave per matrix, rows in registers + shuffles.
__global__ void __launch_bounds__(64) k_diag(float* __restrict__ mats,
    float* __restrict__ L11g, float* __restrict__ U11g,
    float* __restrict__ logdet, int k){
  int m = blockIdx.x;
  const float* A = mats + (size_t)m*MSZ;
  int t = threadIdx.x;
  float row[64];
  #pragma unroll
  for(int q=0;q<64;q++)
    row[q] = A[(size_t)(k+t)*1024 + k + q];
  float slog = 0.f;
  #pragma unroll
  for(int c=0;c<64;c++){
    float piv = __shfl(row[c], c);
    slog += logf(fabsf(piv));           // uniform across lanes; lane0's is kept
    float ip = frcp(piv);
    bool below = t > c;
    float lic = below ? row[c]*ip : 0.f;
    row[c] = below ? lic : row[c];
    if(below) L11g[m*4096 + t*64 + c] = lic;
    #pragma unroll
    for(int q=c+1;q<64;q++){
      float uq = __shfl(row[q], c);
      row[q] = fmaf(-lic, uq, row[q]);  // lic==0 for t<=c -> no-op
    }
  }
  #pragma unroll
  for(int q=0;q<64;q++)
    U11g[m*4096 + t*64 + q] = (q>=t) ? row[q] : 0.f;
  if(t==0) logdet[m] += slog;
}

// Fused panel solves (independent of each other):
//   first half of grid.x :  L21 = A21 * U11^-1   (thread per trailing row)
//   second half          :  U12 = L11^-1 * A12   (thread per trailing column)
__global__ void __launch_bounds__(256) k_panel(float* __restrict__ mats,
    const float* __restrict__ L11g, const float* __restrict__ U11g, int k){
  int m = blockIdx.y;
  float* A = mats + (size_t)m*MSZ;
  int rem = 1024 - (k+64);
  int nb = (rem + 255) >> 8;
  int t = threadIdx.x;
  if((int)blockIdx.x < nb){
    // ---- L21 = A21 * U11^-1
    const float* __restrict__ U = U11g + m*4096;
    int i = k + 64 + blockIdx.x*256 + t;
    bool act = i < 1024;
    size_t base = (size_t)i*1024 + k;
    float xr[64];
    const float4* pb = (const float4*)(A + (act ? base : 0));
    #pragma unroll
    for(int q4=0;q4<16;q4++){
      float4 v = act ? pb[q4] : make_float4(0.f,0.f,0.f,0.f);
      xr[4*q4]=v.x; xr[4*q4+1]=v.y; xr[4*q4+2]=v.z; xr[4*q4+3]=v.w;
    }
    #pragma unroll
    for(int p=0;p<64;p++){
      float xp = xr[p]*frcp(U[p*64+p]);
      xr[p] = xp;
      #pragma unroll
      for(int q=p+1;q<64;q++) xr[q] = fmaf(-xp, U[p*64+q], xr[q]);
    }
    if(act){
      float4* po = (float4*)(A + base);
      #pragma unroll
      for(int q4=0;q4<16;q4++)
        po[q4] = make_float4(xr[4*q4],xr[4*q4+1],xr[4*q4+2],xr[4*q4+3]);
    }
  } else {
    // ---- U12 = L11^-1 * A12
    const float* __restrict__ L = L11g + m*4096;
    int col = k + 64 + (blockIdx.x - nb)*256 + t;
    bool act = col < 1024;
    float tv[64];
    #pragma unroll
    for(int r=0;r<64;r++) tv[r] = act ? A[(size_t)(k+r)*1024 + col] : 0.f;
    #pragma unroll
    for(int r=1;r<64;r++){
      float s = tv[r];
      #pragma unroll
      for(int p=0;p<r;p++) s = fmaf(-L[r*64+p], tv[p], s);
      tv[r] = s;
    }
    if(act){
      #pragma unroll
      for(int r=0;r<64;r++) A[(size_t)(k+r)*1024 + col] = tv[r];
    }
  }
}

// A22 -= L21 * U12 : 128x128 tiles, 256 threads, 8x8 micro-tile, K chunked by 16
__global__ void __launch_bounds__(256) k_gemm(float* __restrict__ mats, int k){
  int m = blockIdx.z;
  float* A = mats + (size_t)m*MSZ;
  int r0 = k + 64;
  int i0 = r0 + blockIdx.y*128;
  int j0 = r0 + blockIdx.x*128;
  __shared__ float As[16][132];   // transposed: As[kc][ilocal]
  __shared__ float Bs[16][132];   // natural:    Bs[kc][jlocal]
  int t = threadIdx.x;
  int tx = t & 15, ty = t >> 4;
  float acc[8][8];
  #pragma unroll
  for(int r=0;r<8;r++){
    #pragma unroll
    for(int q=0;q<8;q++) acc[r][q]=0.f;
  }
  for(int ko=0; ko<64; ko+=16){
    #pragma unroll
    for(int h=0; h<2; h++){
      int row = (t>>2) + h*64;          // 0..127
      int c4  = (t&3)*4;                // 0,4,8,12
      float4 v = *(const float4*)(A + (size_t)(i0+row)*1024 + k + ko + c4);
      As[c4+0][row]=v.x; As[c4+1][row]=v.y; As[c4+2][row]=v.z; As[c4+3][row]=v.w;
    }
    #pragma unroll
    for(int h=0; h<2; h++){
      int kk = t>>4;                    // 0..15
      int j4 = (t&15)*4 + h*64;         // 0..124
      float4 v = *(const float4*)(A + (size_t)(k+ko+kk)*1024 + j0 + j4);
      *(float4*)&Bs[kk][j4] = v;
    }
    __syncthreads();
    #pragma unroll
    for(int kk=0; kk<16; kk++){
      float4 a0 = *(const float4*)&As[kk][ty*4];
      float4 a1 = *(const float4*)&As[kk][ty*4+64];
      float4 b0 = *(const float4*)&Bs[kk][tx*4];
      float4 b1 = *(const float4*)&Bs[kk][tx*4+64];
      float a[8] = {a0.x,a0.y,a0.z,a0.w,a1.x,a1.y,a1.z,a1.w};
      float b[8] = {b0.x,b0.y,b0.z,b0.w,b1.x,b1.y,b1.z,b1.w};
      #pragma unroll
      for(int r=0;r<8;r++){
        #pragma unroll
        for(int q=0;q<8;q++) acc[r][q] = fmaf(a[r], b[q], acc[r][q]);
      }
    }
    __syncthreads();
  }
  // coalesced float4 RMW of C
  #pragma unroll
  for(int hi=0; hi<2; hi++){
    #pragma unroll
    for(int r=0;r<4;r++){
      int gi = i0 + hi*64 + ty*4 + r;
      #pragma unroll
      for(int hj=0; hj<2; hj++){
        int gj = j0 + hj*64 + tx*4;
        float4* pc = (float4*)(A + (size_t)gi*1024 + gj);
        float4 c = *pc;
        c.x -= acc[hi*4+r][hj*4+0];
        c.y -= acc[hi*4+r][hj*4+1];
        c.z -= acc[hi*4+r][hj*4+2];
        c.w -= acc[hi*4+r][hj*4+3];
        *pc = c;
      }
    }
  }
}

__global__ void k_final(const float* __restrict__ y, const float* __restrict__ logdet,
                        float* __restrict__ out){
  int b = threadIdx.x;
  if(b<32) out[b] = y[b] + logdet[1+b] - logdet[0];
}

// ---------------------------------------------------------------- launch
extern "C" void kernel_launch(void* const* d_in, const int* in_sizes, int n_in,
                              void* d_out, int out_size, void* d_ws, size_t ws_size,
                              hipStream_t stream){
  (void)in_sizes; (void)n_in; (void)out_size; (void)ws_size;
  const int*   x  = (const int*)d_in[0];
  const float* W  = (const float*)d_in[1];
  const float* Vc = (const float*)d_in[2];
  const float* Ec = (const float*)d_in[3];
  float* out = (float*)d_out;

  char* p = (char*)d_ws;
  auto alloc = [&](size_t bytes)->char*{ char* r = p; p += (bytes+255)&~(size_t)255; return r; };
  float* mats   = (float*)alloc((size_t)NMAT*MSZ*4);   // 138.4 MB: L0 + 32 batch matrices
  float* Ws     = (float*)alloc(1048576ull*4);
  float* L11g   = (float*)alloc((size_t)NMAT*4096*4);
  float* U11g   = (float*)alloc((size_t)NMAT*4096*4);
  float* V      = (float*)alloc(4096*4);
  float* PrInv  = (float*)alloc(32768*4);
  float* col0   = (float*)alloc(32768*4);
  float* y      = (float*)alloc(256);
  float* logdet = (float*)alloc(256);

  k_init<<<1,64,0,stream>>>(logdet);
  k_softmax_v<<<4,256,0,stream>>>(Vc, V);
  k_pr_y<<<32,256,0,stream>>>(V, x, PrInv, y);
  k_ws<<<4096,256,0,stream>>>(W, Ws);
  k_sinkhorn<<<4096,256,0,stream>>>(Ec, V, Ws, PrInv, x, mats, col0);
  k_l0<<<1024,256,0,stream>>>(Ws, mats);
  k_lb<<<dim3(1024,32),256,0,stream>>>(mats, col0);

  for(int s=0;s<16;s++){
    int k = 64*s;
    k_diag<<<NMAT,64,0,stream>>>(mats, L11g, U11g, logdet, k);
    int rem = 1024 - (k+64);
    if(rem > 0){
      int nbp = (rem+255)/256;
      k_panel<<<dim3(2*nbp,NMAT),256,0,stream>>>(mats, L11g, U11g, k);
      int nt = (rem+127)/128;
      k_gemm<<<dim3(nt,nt,NMAT),256,0,stream>>>(mats, k);
    }
  }
  k_final<<<1,32,0,stream>>>(y, logdet, out);
}